// Round 1
// baseline (134.194 us; speedup 1.0000x reference)
//
#include <hip/hip_runtime.h>

// Sequential 1001-step closed-loop double-integrator sim with teacher forcing
// and early stopping. Inherently serial (nonlinear recurrence with division),
// so: 1 block, cooperative staging to LDS, then lane 0 runs the scan.

#define N_STEPS 1001
#define DT_F 0.05f
#define LO_F 0.05f
#define HI_F 1000.0f

__global__ __launch_bounds__(256) void sim_scan_kernel(
    const float* __restrict__ inputs,
    const float* __restrict__ fc1_w,
    const void* __restrict__ tf_mask,
    float* __restrict__ out)
{
    __shared__ float s_u[N_STEPS];
    __shared__ unsigned char s_tf[N_STEPS];
    __shared__ int s_width;

    const int tid = threadIdx.x;

    // Zero the entire output (outputs after the stop step must be 0, and the
    // harness poisons d_out with 0xAA before timing without re-poisoning).
    for (int i = tid; i < N_STEPS + 1; i += 256) out[i] = 0.0f;

    // --- detect tf_mask element width (bool/u8 vs int32 vs int64) ---
    // int32 0/1 values: bytes at offsets i%4!=0 are always 0.
    // int64 0/1 values: additionally bytes at i%8==4 are always 0.
    // 1-byte bool: offsets 1..399 hold ~300 random 0/1 bytes -> some nonzero
    // with probability 1 - 2^-300.
    if (tid == 0) {
        const unsigned char* mb = (const unsigned char*)tf_mask;
        bool any_nonmult4 = false, any_mod8_4 = false;
        for (int i = 1; i < 400; ++i) {
            unsigned char b = mb[i];
            if (b) {
                if ((i & 3) != 0) any_nonmult4 = true;
                else if ((i & 7) == 4) any_mod8_4 = true;
            }
        }
        s_width = any_nonmult4 ? 1 : (any_mod8_4 ? 4 : 8);
    }
    __syncthreads();

    // --- cooperative staging: inputs and normalized mask into LDS ---
    const int width = s_width;
    const unsigned char* mb = (const unsigned char*)tf_mask;
    for (int k = tid; k < N_STEPS; k += 256) {
        s_u[k] = inputs[k];
        bool tf;
        if (width == 1)      tf = mb[k] != 0;
        else if (width == 4) tf = ((const int*)tf_mask)[k] != 0;
        else                 tf = ((const long long*)tf_mask)[k] != 0;
        s_tf[k] = (unsigned char)tf;
    }
    __syncthreads();

    if (tid != 0) return;

    const float w  = fc1_w[0];
    const float c1 = DT_F * DT_F * 0.5f;  // dt^2/2

    float p = 100.0f;  // state[0]
    float v = 0.0f;    // state[1]
    int k_stop = N_STEPS - 1;

    for (int k = 0; k < N_STEPS; ++k) {
        const float u = s_u[k];
        const bool tf = s_tf[k] != 0;

        // teacher forcing: state_in = [p, p*u] (stop_gradient is identity fwd)
        const float p_in = p;
        const float v_in = tf ? (p * u) : v;

        // net_in = u - v_in/p_in  (literal, matches reference even when tf)
        const float net_in = u - v_in / p_in;
        const float f = w * net_in;  // fc1: Linear(1,1,bias=False)

        // new_state = A @ state_in + B * f  (Tustin, exact for double integrator)
        const float pn = p_in + DT_F * v_in + c1 * f;
        const float vn = v_in + DT_F * f;

        // out emitted on the hit step itself (mask uses PREVIOUS stopped flag)
        out[k] = vn / pn;

        p = pn;
        v = vn;

        if (pn < LO_F || pn > HI_F) { k_stop = k; break; }
    }

    out[N_STEPS] = (float)k_stop;  // k_stop, written as float (flat f32 output)
}

extern "C" void kernel_launch(void* const* d_in, const int* in_sizes, int n_in,
                              void* d_out, int out_size, void* d_ws, size_t ws_size,
                              hipStream_t stream) {
    const float* inputs = (const float*)d_in[0];
    const float* fc1_w  = (const float*)d_in[1];
    const void*  tfm    = d_in[2];
    (void)in_sizes; (void)n_in; (void)out_size; (void)d_ws; (void)ws_size;

    sim_scan_kernel<<<dim3(1), dim3(256), 0, stream>>>(
        inputs, fc1_w, tfm, (float*)d_out);
}